// Round 8
// baseline (386.051 us; speedup 1.0000x reference)
//
#include <hip/hip_runtime.h>
#include <math.h>

// MoE top-2 router. Round 11: pure-VALU fp32 GEMV-broadcast. Seven rounds
// proved hipcc can't sustain an MFMA feed pipeline at HIP source level:
// barrier'd LDS variants drain vmcnt at every chunk (80-104us), register
// prefetch gets collapsed by regalloc (VGPR 88/44/32 -> loads sunk to use).
// With E=64 this op is 4.3 GFLOP of fp32 FMA = ~30us at VALU rate -- same
// order as the memory floor -- and the GEMV-broadcast structure is
// stall-proof: W indices are wave-uniform -> SGPR (s_load) broadcast, x
// streams per-lane (L1-resident rows), acc[16]/thread, 64 independent FMAs
// per k4-step, ZERO barriers in the k-loop, no inter-wave coupling.
// Block = 1024 threads = 16 waves = (4 expert-quarters x 4 k-quarters),
// lanes = 64 tokens. One LDS exchange (68-padded, conflict-free reads) then
// the session-verified 64-lane softmax/top-2 epilogue. No convert_w, no
// workspace, full fp32 accuracy.
//
// x: [16384, 2048] fp32, W: [64, 2048] fp32.
// outputs (concat, fp32): mask [T,64], idx-as-float [T,2],
//                         router_probs [T,64], probs [T,64]

#define D_DIM 2048
#define E_DIM 64

// ---- fused GEMV + softmax + top-2 + outputs ----
// grid = T/64 blocks of 1024 threads (16 waves/CU = 4 waves/SIMD).
// wave wv: expert quarter eq = wv>>2 (experts eq*16..+16),
//          k quarter     kq = wv&3  (k in [kq*512, kq*512+512)).
// lane = token within the block's 64-token tile.
__global__ __launch_bounds__(1024, 4) void router_fused(
    const float* __restrict__ x, const float* __restrict__ Wg,
    float* __restrict__ mask_out, float* __restrict__ idx_out,
    float* __restrict__ rp_out, float* __restrict__ probs_out)
{
    // partial logits: [kq][token][expert], stride 68 floats
    // (16B-aligned rows; epilogue reads hit all 32 banks, 2 lanes/bank).
    __shared__ __align__(16) float Lp[4][64][68];   // 68 KB

    const int tid  = threadIdx.x;
    const int lane = tid & 63;
    const int wv   = tid >> 6;                       // 0..15

    const int t0 = blockIdx.x << 6;

    // force wave-uniformity so W addresses become scalar (s_load broadcast)
    const int eq = __builtin_amdgcn_readfirstlane(wv >> 2);
    const int kq = __builtin_amdgcn_readfirstlane(wv & 3);

    const float* xq = x  + (size_t)(t0 + lane) * D_DIM + kq * 512;
    const float* Wq = Wg + (size_t)(eq * 16) * D_DIM + kq * 512;

    float acc[16];
    #pragma unroll
    for (int e = 0; e < 16; ++e) acc[e] = 0.f;

    // ---- k-loop: 128 steps of 4k; 64 independent FMAs per step; no barriers.
    for (int j = 0; j < 512; j += 4) {
        const float4 xv = *(const float4*)(xq + j);
        #pragma unroll
        for (int e = 0; e < 16; ++e) {
            const float* wp = Wq + e * D_DIM + j;    // wave-uniform -> s_load
            float a = acc[e];
            a = fmaf(xv.x, wp[0], a);
            a = fmaf(xv.y, wp[1], a);
            a = fmaf(xv.z, wp[2], a);
            a = fmaf(xv.w, wp[3], a);
            acc[e] = a;
        }
    }

    // ---- exchange partials (one ds_write_b128 x4 per thread) ----
    #pragma unroll
    for (int e = 0; e < 16; e += 4) {
        float4 v4 = make_float4(acc[e], acc[e + 1], acc[e + 2], acc[e + 3]);
        *(float4*)&Lp[kq][lane][eq * 16 + e] = v4;
    }
    __syncthreads();

    // ---- verified 64-lane softmax / top-2 / writeout; wave per 4 tokens ----
    #pragma unroll
    for (int i = 0; i < 4; ++i) {
        const int tl = wv * 4 + i;                   // token within block
        const int t  = t0 + tl;
        const float v = Lp[0][tl][lane] + Lp[1][tl][lane]
                      + Lp[2][tl][lane] + Lp[3][tl][lane];

        // argmax, lower-index tie-break (matches jax.lax.top_k)
        float bv = v; int bi = lane;
        #pragma unroll
        for (int off = 1; off < 64; off <<= 1) {
            float ov = __shfl_xor(bv, off, 64);
            int   oi = __shfl_xor(bi, off, 64);
            bool take = (ov > bv) || (ov == bv && oi < bi);
            bv = take ? ov : bv;
            bi = take ? oi : bi;
        }
        const float m = bv; const int i1 = bi;

        const float p = __expf(v - m);
        float s = p;
        #pragma unroll
        for (int off = 1; off < 64; off <<= 1) s += __shfl_xor(s, off, 64);
        const float prob = p / s;

        // second argmax excluding i1
        const float v2 = (lane == i1) ? -INFINITY : v;
        float cv = v2; int ci = lane;
        #pragma unroll
        for (int off = 1; off < 64; off <<= 1) {
            float ov = __shfl_xor(cv, off, 64);
            int   oi = __shfl_xor(ci, off, 64);
            bool take = (ov > cv) || (ov == cv && oi < ci);
            cv = take ? ov : cv;
            ci = take ? oi : ci;
        }
        const int i2 = ci;

        const float pd = __shfl(prob, i1, 64) + __shfl(prob, i2, 64);
        const bool top = (lane == i1) || (lane == i2);

        const size_t base = (size_t)t * 64 + lane;
        mask_out[base]  = top ? 1.f : 0.f;
        rp_out[base]    = top ? prob / pd : 0.f;
        probs_out[base] = prob;
        if (lane == 0) {
            idx_out[(size_t)t * 2]     = (float)i1;
            idx_out[(size_t)t * 2 + 1] = (float)i2;
        }
    }
}

extern "C" void kernel_launch(void* const* d_in, const int* in_sizes, int n_in,
                              void* d_out, int out_size, void* d_ws, size_t ws_size,
                              hipStream_t stream) {
    const float* x = (const float*)d_in[0];
    const float* W = (const float*)d_in[1];
    float* out = (float*)d_out;

    const int T = in_sizes[0] / D_DIM;      // 16384 tokens

    float* mask_out  = out;
    float* idx_out   = out + (size_t)T * E_DIM;
    float* rp_out    = idx_out + (size_t)T * 2;
    float* probs_out = rp_out + (size_t)T * E_DIM;

    router_fused<<<dim3(T / 64), dim3(1024), 0, stream>>>(
        x, W, mask_out, idx_out, rp_out, probs_out);
}